// Round 13
// baseline (569.744 us; speedup 1.0000x reference)
//
#include <hip/hip_runtime.h>

#define BB 1024
#define FF 64
#define SS 512
#define HH 128
#define ZP 200          // z row pitch in bf16 elems (192 data + 8 pad)
#define ZROWS 16
#define OUTS (BB*FF)

typedef __attribute__((ext_vector_type(8))) short bf16x8;
typedef __attribute__((ext_vector_type(4))) float f32x4;

__device__ __forceinline__ unsigned short f2bf(float f) {
    unsigned int u = __float_as_uint(f);
    u += 0x7fff + ((u >> 16) & 1);          // RNE
    return (unsigned short)(u >> 16);
}

// LDS-only barrier: fused waitcnt+s_barrier under one "memory" clobber;
// sched_barrier(0) fences the machine scheduler on both sides (rule #18).
__device__ __forceinline__ void bar_lds() {
    __builtin_amdgcn_sched_barrier(0);
    asm volatile("s_waitcnt lgkmcnt(0)\n\ts_barrier" ::: "memory");
    __builtin_amdgcn_sched_barrier(0);
}

// ---------------------------------------------------------------------------
// Fold kernel: W_fold[n][k] = sum_f W_ih[n][f]*W_den[f][k],
// b_fold[n]   = sum_f W_ih[n][f]*b_den[f].
// ws floats: [0,65536) W_fold, [65536,66048) b_fold; ints at 66048: perm.
// ---------------------------------------------------------------------------
__global__ void fold_kernel(const float* __restrict__ W_ih,
                            const float* __restrict__ W_den,
                            const float* __restrict__ b_den,
                            float* __restrict__ ws)
{
    const int n = blockIdx.x;      // 512
    const int k = threadIdx.x;     // 128
    float s = 0.f;
    #pragma unroll 8
    for (int f = 0; f < FF; ++f) s = fmaf(W_ih[n*FF + f], W_den[f*HH + k], s);
    ws[n*HH + k] = s;
    if (k == 0) {
        float bsum = 0.f;
        #pragma unroll 8
        for (int f = 0; f < FF; ++f) bsum = fmaf(W_ih[n*FF + f], b_den[f], bsum);
        ws[4*HH*HH + n] = bsum;
    }
}

// ---------------------------------------------------------------------------
// Rank-sort rows by available_len (LDS-staged, parallel: 4 blocks x 256).
// perm[rank] = row; deterministic tie-break by index.
// ---------------------------------------------------------------------------
__global__ void sort_kernel(const int* __restrict__ avail, int* __restrict__ perm)
{
    __shared__ int keys[BB];
    const int t = threadIdx.x;
    for (int i = t; i < BB; i += 256) keys[i] = avail[i];
    __syncthreads();
    const int i = blockIdx.x * 256 + t;
    const int key = keys[i];
    int rank = 0;
    #pragma unroll 8
    for (int j = 0; j < BB; ++j) {
        const int kj = keys[j];
        rank += (kj < key) || (kj == key && j < i);
    }
    perm[rank] = i;
}

// ---------------------------------------------------------------------------
// Main recurrence: 256 blocks x 256 THREADS (4 waves, 1 wave/SIMD).
// launch_bounds(256,1) -> full 512-reg unified budget per thread (the 512-thr
// variants were hard-capped at 256: 128 VGPR + 128 AGPR; 8-wave lockstep was
// the step-cost floor). Wave w owns units [32w,32w+32) = 2 col-tiles; lane's
// acc[.][0] = its row. Block owns 4 AV-sorted rows at M-rows {0,4,8,12}.
// PHASE 0 [0,minAV-1): teacher, 1 barrier, pred deferred 1 step.
// PHASE 1 [minAV-1,maxAV): 2-barrier mixed (feedback at B2), ~1-3 steps.
// PHASE 2 [maxAV,maxP): W_auto fold, 1 barrier, deferred pred.
// ---------------------------------------------------------------------------
__global__ __launch_bounds__(256, 1)
void lstm_mfma_kernel(const float* __restrict__ x,
                      const int* __restrict__ available_len,
                      const int* __restrict__ predict_len,
                      const float* __restrict__ W_ih,
                      const float* __restrict__ W_hh,
                      const float* __restrict__ b_ih,
                      const float* __restrict__ b_hh,
                      const float* __restrict__ W_den,
                      const float* __restrict__ b_den,
                      const float* __restrict__ init_ch,
                      const float* __restrict__ ws,
                      const int* __restrict__ perm,
                      float* __restrict__ out)
{
    const int b0  = blockIdx.x * 4;
    const int tid = threadIdx.x;
    const int w   = tid >> 6;          // wave 0..3
    const int l   = tid & 63;
    const int l16 = l & 15;
    const int lq  = l >> 4;            // 0..3

    __shared__ __align__(16) unsigned short zbuf[2][ZROWS * ZP];

    for (int i = tid; i < 2 * ZROWS * ZP / 2; i += 256)
        ((unsigned int*)zbuf)[i] = 0u;

    const int rr0 = perm[b0], rr1 = perm[b0+1], rr2 = perm[b0+2], rr3 = perm[b0+3];
    const int p0 = predict_len[rr0], p1 = predict_len[rr1],
              p2 = predict_len[rr2], p3 = predict_len[rr3];
    const int a0i = available_len[rr0], a1i = available_len[rr1],
              a2i = available_len[rr2], a3i = available_len[rr3];
    const int maxP  = max(max(p0, p1), max(p2, p3));
    const int tsw   = max(max(a0i, a1i), max(a2i, a3i));   // phase-2 start
    const int tmin  = min(min(a0i, a1i), min(a2i, a3i));
    const int ph1s  = (tmin > 1) ? (tmin - 1) : 0;         // phase-1 start
    const int rl    = perm[b0 + lq];            // lane's row
    const int P_my  = predict_len[rl];
    const int AV_my = available_len[rl];

    // ---- gate weights: wg[gate][coltile][ktile], 192 regs ----
    bf16x8 wg[4][2][6];
    float bias[4][2];
    #pragma unroll
    for (int g = 0; g < 4; ++g) {
        #pragma unroll
        for (int ct = 0; ct < 2; ++ct) {
            const int n = 128*g + 32*w + 16*ct + l16;
            const float* rih = W_ih + n * FF;
            const float* rhh = W_hh + n * HH;
            #pragma unroll
            for (int kt = 0; kt < 6; ++kt) {
                const int k = 32*kt + 8*lq;
                const float* src = (k < 64) ? (rih + k) : (rhh + (k - 64));
                bf16x8 r;
                #pragma unroll
                for (int i = 0; i < 8; i++) r[i] = (short)f2bf(src[i]);
                wg[g][ct][kt] = r;
            }
            bias[g][ct] = b_ih[n] + b_hh[n];
        }
    }

    // pred weights: f = 16w + l16 (4 waves cover 64 features)
    bf16x8 wd[4];
    float bden;
    {
        const int f = 16*w + l16;
        const float* rd = W_den + f * HH;
        #pragma unroll
        for (int kt = 0; kt < 4; ++kt) {
            const int k = 32*kt + 8*lq;
            bf16x8 r;
            #pragma unroll
            for (int i = 0; i < 8; i++) r[i] = (short)f2bf(rd[k + i]);
            wd[kt] = r;
        }
        bden = b_den[f];
    }

    // x duty: wave w streams sorted row perm[b0+w], feature l
    const int rx = perm[b0 + w];
    const size_t xbase = ((size_t)rx * FF + l) * SS;
    const int AV_x = available_len[rx];

    const int u0 = 32*w + l16;         // this lane's two hidden units
    const int u1 = u0 + 16;
    const int abase = l16*ZP + 8*lq;
    float cc0 = init_ch[u0], cc1 = init_ch[u1];
    const float h0v0 = init_ch[HH + u0], h0v1 = init_ch[HH + u1];
    float* outb = out + (size_t)rl * FF + 16*w + l16;

    bar_lds();                          // zeroing visible before init writes

    zbuf[0][(4*lq)*ZP + 64 + u0] = f2bf(h0v0);
    zbuf[0][(4*lq)*ZP + 64 + u1] = f2bf(h0v1);
    zbuf[0][(4*w)*ZP + l] = f2bf(x[xbase]);

    float4 qc = {0.f,0.f,0.f,0.f};
    if (AV_x > 1) qc = *(const float4*)(x + xbase);   // x_0..x_3

    int cur = 0;

    // gate MFMA block over 6 A-frags (phase 0/1) --------------------------
#define GATES6(AV)                                                             \
    f32x4 ag[4][2];                                                            \
    _Pragma("unroll")                                                          \
    for (int g = 0; g < 4; ++g) { ag[g][0] = (f32x4){0.f,0.f,0.f,0.f};         \
                                  ag[g][1] = (f32x4){0.f,0.f,0.f,0.f}; }       \
    _Pragma("unroll")                                                          \
    for (int kt = 0; kt < 6; ++kt) {                                           \
      _Pragma("unroll")                                                        \
      for (int g = 0; g < 4; ++g) {                                            \
        ag[g][0] = __builtin_amdgcn_mfma_f32_16x16x32_bf16(AV[kt], wg[g][0][kt], ag[g][0], 0,0,0); \
        ag[g][1] = __builtin_amdgcn_mfma_f32_16x16x32_bf16(AV[kt], wg[g][1][kt], ag[g][1], 0,0,0); \
      }                                                                        \
    }

    // cell update + h write for the lane's 2 units -------------------------
#define CELL2(S, NXT)                                                          \
    _Pragma("unroll")                                                          \
    for (int ct = 0; ct < 2; ++ct) {                                           \
      const float g0 = ag[0][ct][0] + bias[0][ct];                             \
      const float g1 = ag[1][ct][0] + bias[1][ct];                             \
      const float g2 = ag[2][ct][0] + bias[2][ct];                             \
      const float g3 = ag[3][ct][0] + bias[3][ct];                             \
      const float si = 1.f / (1.f + __expf(-g0));                              \
      const float sf = 1.f / (1.f + __expf(-g1));                              \
      const float tg = 1.f - 2.f / (__expf(2.f * g2) + 1.f);                   \
      const float so = 1.f / (1.f + __expf(-g3));                              \
      const float cn = sf * (ct ? cc1 : cc0) + si * tg;                        \
      const float tc = 1.f - 2.f / (__expf(2.f * cn) + 1.f);                   \
      const float hn = so * tc;                                                \
      if ((S) < P_my) {                                                        \
        if (ct) cc1 = cn; else cc0 = cn;                                       \
        zbuf[NXT][(4*lq)*ZP + 64 + (ct ? u1 : u0)] = f2bf(hn);                 \
      }                                                                        \
    }

    // ============ PHASE 0: t in [0, ph1s) — pure teacher, 1 barrier =========
#define DO_T(S, XNEXT)                                                         \
  do {                                                                         \
    const int s_ = (S);                                                        \
    bar_lds();                                                                 \
    const unsigned short* zc_ = zbuf[cur];                                     \
    bf16x8 av[6];                                                              \
    av[0] = *(const bf16x8*)(zc_ + abase +   0);                               \
    av[1] = *(const bf16x8*)(zc_ + abase +  32);                               \
    av[2] = *(const bf16x8*)(zc_ + abase +  64);                               \
    av[3] = *(const bf16x8*)(zc_ + abase +  96);                               \
    av[4] = *(const bf16x8*)(zc_ + abase + 128);                               \
    av[5] = *(const bf16x8*)(zc_ + abase + 160);                               \
    if (s_ >= 1) {                       /* deferred pred_{s-1} = Wden.h_s */  \
      f32x4 ca = {0.f,0.f,0.f,0.f}, cb = {0.f,0.f,0.f,0.f};                    \
      ca = __builtin_amdgcn_mfma_f32_16x16x32_bf16(av[2], wd[0], ca, 0,0,0);   \
      cb = __builtin_amdgcn_mfma_f32_16x16x32_bf16(av[4], wd[2], cb, 0,0,0);   \
      ca = __builtin_amdgcn_mfma_f32_16x16x32_bf16(av[3], wd[1], ca, 0,0,0);   \
      cb = __builtin_amdgcn_mfma_f32_16x16x32_bf16(av[5], wd[3], cb, 0,0,0);   \
      if ((s_ - 1) < P_my) outb[(size_t)(s_-1) * OUTS] = ca[0] + cb[0] + bden; \
    }                                                                          \
    GATES6(av)                                                                 \
    const int nxt_ = cur ^ 1;                                                  \
    CELL2(s_, nxt_)                                                            \
    if (s_ + 1 < AV_x) zbuf[nxt_][(4*w)*ZP + l] = f2bf(XNEXT);                 \
    cur = nxt_;                                                                \
  } while (0)

    // ============ PHASE 1 step: 2-barrier mixed (+ catch-up pred) ===========
#define DO_STEP(S, XNEXT)                                                      \
  do {                                                                         \
    const int s_ = (S);                                                        \
    bar_lds();                                          /* B1 */               \
    const unsigned short* zc_ = zbuf[cur];                                     \
    bf16x8 av[6];                                                              \
    av[0] = *(const bf16x8*)(zc_ + abase +   0);                               \
    av[1] = *(const bf16x8*)(zc_ + abase +  32);                               \
    av[2] = *(const bf16x8*)(zc_ + abase +  64);                               \
    av[3] = *(const bf16x8*)(zc_ + abase +  96);                               \
    av[4] = *(const bf16x8*)(zc_ + abase + 128);                               \
    av[5] = *(const bf16x8*)(zc_ + abase + 160);                               \
    if (s_ >= 1) {                       /* catch-up pred_{s-1} (dup-safe) */  \
      f32x4 ca = {0.f,0.f,0.f,0.f}, cb = {0.f,0.f,0.f,0.f};                    \
      ca = __builtin_amdgcn_mfma_f32_16x16x32_bf16(av[2], wd[0], ca, 0,0,0);   \
      cb = __builtin_amdgcn_mfma_f32_16x16x32_bf16(av[4], wd[2], cb, 0,0,0);   \
      ca = __builtin_amdgcn_mfma_f32_16x16x32_bf16(av[3], wd[1], ca, 0,0,0);   \
      cb = __builtin_amdgcn_mfma_f32_16x16x32_bf16(av[5], wd[3], cb, 0,0,0);   \
      if ((s_ - 1) < P_my) outb[(size_t)(s_-1) * OUTS] = ca[0] + cb[0] + bden; \
    }                                                                          \
    GATES6(av)                                                                 \
    const int nxt_ = cur ^ 1;                                                  \
    CELL2(s_, nxt_)                                                            \
    if (s_ + 1 < AV_x) zbuf[nxt_][(4*w)*ZP + l] = f2bf(XNEXT);                 \
    bar_lds();                                          /* B2: h ready */      \
    {                                                                          \
      const unsigned short* zn_ = zbuf[nxt_];                                  \
      bf16x8 h0f = *(const bf16x8*)(zn_ + abase + 64 +  0);                    \
      bf16x8 h1f = *(const bf16x8*)(zn_ + abase + 64 + 32);                    \
      bf16x8 h2f = *(const bf16x8*)(zn_ + abase + 64 + 64);                    \
      bf16x8 h3f = *(const bf16x8*)(zn_ + abase + 64 + 96);                    \
      f32x4 pa = {0.f,0.f,0.f,0.f}, pb = {0.f,0.f,0.f,0.f};                    \
      pa = __builtin_amdgcn_mfma_f32_16x16x32_bf16(h0f, wd[0], pa, 0,0,0);     \
      pb = __builtin_amdgcn_mfma_f32_16x16x32_bf16(h2f, wd[2], pb, 0,0,0);     \
      pa = __builtin_amdgcn_mfma_f32_16x16x32_bf16(h1f, wd[1], pa, 0,0,0);     \
      pb = __builtin_amdgcn_mfma_f32_16x16x32_bf16(h3f, wd[3], pb, 0,0,0);     \
      const float pred_ = pa[0] + pb[0] + bden;                                \
      if (s_ < P_my) {                                                         \
        outb[(size_t)s_ * OUTS] = pred_;                                       \
        if (s_ + 1 >= AV_my)                                                   \
          zbuf[nxt_][(4*lq)*ZP + 16*w + l16] = f2bf(pred_);                    \
      }                                                                        \
    }                                                                          \
    cur = nxt_;                                                                \
  } while (0)

    int t4 = 0;
    for (; t4 + 4 <= ph1s; t4 += 4) {                  // phase 0 (quad x)
        float4 qn = {0.f,0.f,0.f,0.f};
        if (t4 + 4 < AV_x)
            qn = *(const float4*)(x + xbase + t4 + 4);
        DO_T(t4 + 0, qc.y);
        DO_T(t4 + 1, qc.z);
        DO_T(t4 + 2, qc.w);
        DO_T(t4 + 3, qn.x);
        qc = qn;
    }
    for (; t4 < ph1s; ++t4) {                          // phase 0 remainder
        float xs = 0.f;
        if (t4 + 1 < AV_x) xs = x[xbase + t4 + 1];
        DO_T(t4, xs);
    }
    for (; t4 < tsw; ++t4) {                           // phase 1 (short)
        float xs = 0.f;
        if (t4 + 1 < AV_x) xs = x[xbase + t4 + 1];
        DO_STEP(t4, xs);
    }
#undef DO_T
#undef DO_STEP

    // ============ PHASE 2: t in [tsw, maxP) — all rows auto (fold) ==========
    if (tsw < maxP) {
        const float* wfold = ws;
        const float* bfold = ws + 4*HH*HH;
        #pragma unroll
        for (int g = 0; g < 4; ++g) {
            #pragma unroll
            for (int ct = 0; ct < 2; ++ct) {
                const int n = 128*g + 32*w + 16*ct + l16;
                const float* rhh = W_hh + n * HH;
                const float* rfo = wfold + n * HH;
                #pragma unroll
                for (int j = 0; j < 4; ++j) {
                    const int k = 32*j + 8*lq;
                    bf16x8 r;
                    #pragma unroll
                    for (int i = 0; i < 8; i++) r[i] = (short)f2bf(rhh[k+i] + rfo[k+i]);
                    wg[g][ct][j] = r;
                }
                bias[g][ct] += bfold[n];
            }
        }

        for (int t = tsw; t < maxP; ++t) {
            bar_lds();                                 // single barrier
            const unsigned short* zc = zbuf[cur];
            bf16x8 hv[4];
            hv[0] = *(const bf16x8*)(zc + abase + 64 +  0);
            hv[1] = *(const bf16x8*)(zc + abase + 64 + 32);
            hv[2] = *(const bf16x8*)(zc + abase + 64 + 64);
            hv[3] = *(const bf16x8*)(zc + abase + 64 + 96);

            {                                          // deferred pred_{t-1}
                f32x4 pa = {0.f,0.f,0.f,0.f}, pb = {0.f,0.f,0.f,0.f};
                pa = __builtin_amdgcn_mfma_f32_16x16x32_bf16(hv[0], wd[0], pa, 0,0,0);
                pb = __builtin_amdgcn_mfma_f32_16x16x32_bf16(hv[2], wd[2], pb, 0,0,0);
                pa = __builtin_amdgcn_mfma_f32_16x16x32_bf16(hv[1], wd[1], pa, 0,0,0);
                pb = __builtin_amdgcn_mfma_f32_16x16x32_bf16(hv[3], wd[3], pb, 0,0,0);
                if ((t - 1) < P_my)                    // dup store at t=tsw is bit-identical
                    outb[(size_t)(t-1) * OUTS] = pa[0] + pb[0] + bden;
            }

            f32x4 ag[4][2];
            #pragma unroll
            for (int g = 0; g < 4; ++g) { ag[g][0] = (f32x4){0.f,0.f,0.f,0.f};
                                          ag[g][1] = (f32x4){0.f,0.f,0.f,0.f}; }
            #pragma unroll
            for (int kt = 0; kt < 4; ++kt) {
                #pragma unroll
                for (int g = 0; g < 4; ++g) {
                    ag[g][0] = __builtin_amdgcn_mfma_f32_16x16x32_bf16(hv[kt], wg[g][0][kt], ag[g][0], 0,0,0);
                    ag[g][1] = __builtin_amdgcn_mfma_f32_16x16x32_bf16(hv[kt], wg[g][1][kt], ag[g][1], 0,0,0);
                }
            }

            const int nxt = cur ^ 1;
            CELL2(t, nxt)
            cur = nxt;
        }

        // epilogue: pred_{maxP-1} from h_{maxP}
        bar_lds();
        {
            const unsigned short* zc = zbuf[cur];
            bf16x8 h0f = *(const bf16x8*)(zc + abase + 64 +  0);
            bf16x8 h1f = *(const bf16x8*)(zc + abase + 64 + 32);
            bf16x8 h2f = *(const bf16x8*)(zc + abase + 64 + 64);
            bf16x8 h3f = *(const bf16x8*)(zc + abase + 64 + 96);
            f32x4 pa = {0.f,0.f,0.f,0.f}, pb = {0.f,0.f,0.f,0.f};
            pa = __builtin_amdgcn_mfma_f32_16x16x32_bf16(h0f, wd[0], pa, 0,0,0);
            pb = __builtin_amdgcn_mfma_f32_16x16x32_bf16(h2f, wd[2], pb, 0,0,0);
            pa = __builtin_amdgcn_mfma_f32_16x16x32_bf16(h1f, wd[1], pa, 0,0,0);
            pb = __builtin_amdgcn_mfma_f32_16x16x32_bf16(h3f, wd[3], pb, 0,0,0);
            if ((maxP - 1) < P_my)
                outb[(size_t)(maxP-1) * OUTS] = pa[0] + pb[0] + bden;
        }
    }
#undef GATES6
#undef CELL2
}

// ---------------------------------------------------------------------------
// Tail: for t >= predict_len[b], out[t][b][f] = x[b][f][t].
// ---------------------------------------------------------------------------
__global__ void tail_copy(const float* __restrict__ x,
                          const int* __restrict__ predict_len,
                          float* __restrict__ out)
{
    __shared__ float tile[64][65];
    const int b  = blockIdx.x;
    const int t0 = blockIdx.y * 64;
    const int P  = predict_len[b];
    if (t0 + 64 <= P) return;

    const int tid = threadIdx.x;         // 256
    const int tt  = tid & 63;
    const int fb  = tid >> 6;
    #pragma unroll
    for (int i = 0; i < 16; i++) {
        int f = fb * 16 + i;
        tile[f][tt] = x[(size_t)b * FF * SS + (size_t)f * SS + t0 + tt];
    }
    __syncthreads();
    const int f2 = tid & 63;
    const int tb = tid >> 6;
    #pragma unroll
    for (int i = 0; i < 16; i++) {
        int tloc = tb * 16 + i;
        int t    = t0 + tloc;
        if (t >= P) out[(size_t)t * BB * FF + (size_t)b * FF + f2] = tile[f2][tloc];
    }
}

extern "C" void kernel_launch(void* const* d_in, const int* in_sizes, int n_in,
                              void* d_out, int out_size, void* d_ws, size_t ws_size,
                              hipStream_t stream) {
    const float* x       = (const float*)d_in[0];
    const int*   avail   = (const int*)  d_in[1];
    const int*   plen    = (const int*)  d_in[2];
    const float* W_ih    = (const float*)d_in[3];
    const float* W_hh    = (const float*)d_in[4];
    const float* b_ih    = (const float*)d_in[5];
    const float* b_hh    = (const float*)d_in[6];
    const float* W_den   = (const float*)d_in[7];
    const float* b_den   = (const float*)d_in[8];
    const float* init_ch = (const float*)d_in[9];
    float*       out     = (float*)d_out;
    float*       ws      = (float*)d_ws;       // 264KB fold + 4KB perm
    int*         perm    = (int*)(ws + 4*HH*HH + 4*HH);

    fold_kernel<<<dim3(4*HH), dim3(HH), 0, stream>>>(W_ih, W_den, b_den, ws);
    sort_kernel<<<dim3(4), dim3(256), 0, stream>>>(avail, perm);
    tail_copy<<<dim3(BB, SS/64), dim3(256), 0, stream>>>(x, plen, out);
    lstm_mfma_kernel<<<dim3(BB/4), dim3(256), 0, stream>>>(
        x, avail, plen, W_ih, W_hh, b_ih, b_hh, W_den, b_den, init_ch, ws, perm, out);
}

// Round 14
// 439.351 us; speedup vs baseline: 1.2968x; 1.2968x over previous
//
#include <hip/hip_runtime.h>

#define BB 1024
#define FF 64
#define SS 512
#define HH 128
#define ZP 200          // z row pitch in bf16 elems (192 data + 8 pad)
#define ZROWS 16
#define OUTS (BB*FF)

typedef __attribute__((ext_vector_type(8))) short bf16x8;
typedef __attribute__((ext_vector_type(4))) float f32x4;

__device__ __forceinline__ unsigned short f2bf(float f) {
    unsigned int u = __float_as_uint(f);
    u += 0x7fff + ((u >> 16) & 1);          // RNE
    return (unsigned short)(u >> 16);
}

// LDS-only barrier: fused waitcnt+s_barrier under one "memory" clobber;
// sched_barrier(0) fences the machine scheduler on both sides (rule #18).
__device__ __forceinline__ void bar_lds() {
    __builtin_amdgcn_sched_barrier(0);
    asm volatile("s_waitcnt lgkmcnt(0)\n\ts_barrier" ::: "memory");
    __builtin_amdgcn_sched_barrier(0);
}

// ---------------------------------------------------------------------------
// Fold kernel: W_fold[n][k] = sum_f W_ih[n][f]*W_den[f][k],
// b_fold[n]   = sum_f W_ih[n][f]*b_den[f].
// ws floats: [0,65536) W_fold, [65536,66048) b_fold; ints at 66560: perm.
// ---------------------------------------------------------------------------
__global__ void fold_kernel(const float* __restrict__ W_ih,
                            const float* __restrict__ W_den,
                            const float* __restrict__ b_den,
                            float* __restrict__ ws)
{
    const int n = blockIdx.x;      // 512
    const int k = threadIdx.x;     // 128
    float s = 0.f;
    #pragma unroll 8
    for (int f = 0; f < FF; ++f) s = fmaf(W_ih[n*FF + f], W_den[f*HH + k], s);
    ws[n*HH + k] = s;
    if (k == 0) {
        float bsum = 0.f;
        #pragma unroll 8
        for (int f = 0; f < FF; ++f) bsum = fmaf(W_ih[n*FF + f], b_den[f], bsum);
        ws[4*HH*HH + n] = bsum;
    }
}

// ---------------------------------------------------------------------------
// Rank-sort rows by available_len (LDS-staged, parallel: 4 blocks x 256;
// validated r13). perm[rank] = row; deterministic tie-break by index.
// ---------------------------------------------------------------------------
__global__ void sort_kernel(const int* __restrict__ avail, int* __restrict__ perm)
{
    __shared__ int keys[BB];
    const int t = threadIdx.x;
    for (int i = t; i < BB; i += 256) keys[i] = avail[i];
    __syncthreads();
    const int i = blockIdx.x * 256 + t;
    const int key = keys[i];
    int rank = 0;
    #pragma unroll 8
    for (int j = 0; j < BB; ++j) {
        const int kj = keys[j];
        rank += (kj < key) || (kj == key && j < i);
    }
    perm[rank] = i;
}

// ---------------------------------------------------------------------------
// Main recurrence (r12 kernel verbatim — best measured: 442us) + merged tail.
// 256 blocks x 512 threads; block owns 4 AV-SORTED rows at M-rows {0,4,8,12}.
// PHASE 0 [0,minAV-1): teacher, 1 barrier, pred deferred 1 step.
// PHASE 1 [minAV-1,maxAV): 2-barrier mixed (feedback at B2), ~1-3 steps.
// PHASE 2 [maxAV,maxP): W_auto fold, 1 barrier, deferred pred.
// EPILOGUE: the block transposes its own 4 rows' tails (t >= P) from x,
// LDS 64x65 tile, both sides coalesced — removes the serial tail_copy
// dispatch; straggler blocks (long P) have short tails.
// ---------------------------------------------------------------------------
__global__ __launch_bounds__(512)
void lstm_mfma_kernel(const float* __restrict__ x,
                      const int* __restrict__ available_len,
                      const int* __restrict__ predict_len,
                      const float* __restrict__ W_ih,
                      const float* __restrict__ W_hh,
                      const float* __restrict__ b_ih,
                      const float* __restrict__ b_hh,
                      const float* __restrict__ W_den,
                      const float* __restrict__ b_den,
                      const float* __restrict__ init_ch,
                      const float* __restrict__ ws,
                      const int* __restrict__ perm,
                      float* __restrict__ out)
{
    const int b0  = blockIdx.x * 4;
    const int tid = threadIdx.x;
    const int w   = tid >> 6;          // wave 0..7
    const int l   = tid & 63;
    const int l16 = l & 15;
    const int lq  = l >> 4;            // 0..3
    const bool w4 = (w < 4);

    __shared__ __align__(16) unsigned short zbuf[2][ZROWS * ZP];
    __shared__ float tile[64][65];     // tail-transpose scratch

    for (int i = tid; i < 2 * ZROWS * ZP / 2; i += 512)
        ((unsigned int*)zbuf)[i] = 0u;

    const int rr0 = perm[b0], rr1 = perm[b0+1], rr2 = perm[b0+2], rr3 = perm[b0+3];
    const int p0 = predict_len[rr0], p1 = predict_len[rr1],
              p2 = predict_len[rr2], p3 = predict_len[rr3];
    const int a0i = available_len[rr0], a1i = available_len[rr1],
              a2i = available_len[rr2], a3i = available_len[rr3];
    const int maxP  = max(max(p0, p1), max(p2, p3));
    const int tsw   = max(max(a0i, a1i), max(a2i, a3i));   // phase-2 start
    const int tmin  = min(min(a0i, a1i), min(a2i, a3i));
    const int ph1s  = (tmin > 1) ? (tmin - 1) : 0;         // phase-1 start
    const int rl    = perm[b0 + lq];            // lane's row
    const int P_my  = predict_len[rl];
    const int AV_my = available_len[rl];

    // ---- gate weights: wg[gate][ktile 0..5], bf16, register-resident ----
    bf16x8 wg[4][6];
    float bias[4];
    #pragma unroll
    for (int g = 0; g < 4; ++g) {
        const int n = 128*g + 16*w + l16;
        const float* rih = W_ih + n * FF;
        const float* rhh = W_hh + n * HH;
        #pragma unroll
        for (int kt = 0; kt < 6; ++kt) {
            const int k = 32*kt + 8*lq;
            const float* src = (k < 64) ? (rih + k) : (rhh + (k - 64));
            bf16x8 r;
            #pragma unroll
            for (int i = 0; i < 8; i++) r[i] = (short)f2bf(src[i]);
            wg[g][kt] = r;
        }
        bias[g] = b_ih[n] + b_hh[n];
    }

    // pred weights (waves 0-3): f = 16w + l16
    bf16x8 wd0, wd1, wd2, wd3;
    float bden = 0.f;
    size_t xbase = 0;
    int AV_x = 0;
    if (w4) {
        const int f = 16*w + l16;
        const float* rd = W_den + f * HH;
        bf16x8 r;
        #pragma unroll
        for (int i = 0; i < 8; i++) r[i] = (short)f2bf(rd[0*32 + 8*lq + i]);
        wd0 = r;
        #pragma unroll
        for (int i = 0; i < 8; i++) r[i] = (short)f2bf(rd[1*32 + 8*lq + i]);
        wd1 = r;
        #pragma unroll
        for (int i = 0; i < 8; i++) r[i] = (short)f2bf(rd[2*32 + 8*lq + i]);
        wd2 = r;
        #pragma unroll
        for (int i = 0; i < 8; i++) r[i] = (short)f2bf(rd[3*32 + 8*lq + i]);
        wd3 = r;
        bden = b_den[f];
        const int rx = perm[b0 + w];            // x duty: sorted row w, feature l
        xbase = ((size_t)rx * FF + l) * SS;
        AV_x  = available_len[rx];
    }

    const int unit  = 16*w + l16;
    const int abase = l16*ZP + 8*lq;
    float c = init_ch[unit];
    const float h0v = init_ch[HH + unit];
    float* outb = out + (size_t)rl * FF + 16*w + l16;

    bar_lds();                          // zeroing visible before init writes

    zbuf[0][(4*lq)*ZP + 64 + unit] = f2bf(h0v);
    if (w4) zbuf[0][(4*w)*ZP + l] = f2bf(x[xbase]);

    float4 qc = {0.f,0.f,0.f,0.f};
    if (AV_x > 1) qc = *(const float4*)(x + xbase);   // x_0..x_3

    int cur = 0;

    // ============ PHASE 0: t in [0, ph1s) — pure teacher, 1 barrier =========
#define DO_T(S, XNEXT)                                                         \
  do {                                                                         \
    const int s_ = (S);                                                        \
    bar_lds();                                          /* single barrier */   \
    const unsigned short* zc_ = zbuf[cur];                                     \
    bf16x8 a0 = *(const bf16x8*)(zc_ + abase +   0);                           \
    bf16x8 a1 = *(const bf16x8*)(zc_ + abase +  32);                           \
    bf16x8 a2 = *(const bf16x8*)(zc_ + abase +  64);                           \
    bf16x8 a3 = *(const bf16x8*)(zc_ + abase +  96);                           \
    bf16x8 a4 = *(const bf16x8*)(zc_ + abase + 128);                           \
    bf16x8 a5 = *(const bf16x8*)(zc_ + abase + 160);                           \
    if (w4 && s_ >= 1) {                 /* deferred pred_{s-1} = Wden.h_s */  \
      f32x4 ca = {0.f,0.f,0.f,0.f}, cb = {0.f,0.f,0.f,0.f};                    \
      ca = __builtin_amdgcn_mfma_f32_16x16x32_bf16(a2, wd0, ca, 0,0,0);        \
      cb = __builtin_amdgcn_mfma_f32_16x16x32_bf16(a4, wd2, cb, 0,0,0);        \
      ca = __builtin_amdgcn_mfma_f32_16x16x32_bf16(a3, wd1, ca, 0,0,0);        \
      cb = __builtin_amdgcn_mfma_f32_16x16x32_bf16(a5, wd3, cb, 0,0,0);        \
      if ((s_ - 1) < P_my) outb[(size_t)(s_-1) * OUTS] = ca[0] + cb[0] + bden; \
    }                                                                          \
    f32x4 ac0 = {0.f,0.f,0.f,0.f}, ac1 = {0.f,0.f,0.f,0.f},                    \
          ac2 = {0.f,0.f,0.f,0.f}, ac3 = {0.f,0.f,0.f,0.f};                    \
    ac0 = __builtin_amdgcn_mfma_f32_16x16x32_bf16(a0, wg[0][0], ac0, 0,0,0);   \
    ac1 = __builtin_amdgcn_mfma_f32_16x16x32_bf16(a0, wg[1][0], ac1, 0,0,0);   \
    ac2 = __builtin_amdgcn_mfma_f32_16x16x32_bf16(a0, wg[2][0], ac2, 0,0,0);   \
    ac3 = __builtin_amdgcn_mfma_f32_16x16x32_bf16(a0, wg[3][0], ac3, 0,0,0);   \
    ac0 = __builtin_amdgcn_mfma_f32_16x16x32_bf16(a1, wg[0][1], ac0, 0,0,0);   \
    ac1 = __builtin_amdgcn_mfma_f32_16x16x32_bf16(a1, wg[1][1], ac1, 0,0,0);   \
    ac2 = __builtin_amdgcn_mfma_f32_16x16x32_bf16(a1, wg[2][1], ac2, 0,0,0);   \
    ac3 = __builtin_amdgcn_mfma_f32_16x16x32_bf16(a1, wg[3][1], ac3, 0,0,0);   \
    ac0 = __builtin_amdgcn_mfma_f32_16x16x32_bf16(a2, wg[0][2], ac0, 0,0,0);   \
    ac1 = __builtin_amdgcn_mfma_f32_16x16x32_bf16(a2, wg[1][2], ac1, 0,0,0);   \
    ac2 = __builtin_amdgcn_mfma_f32_16x16x32_bf16(a2, wg[2][2], ac2, 0,0,0);   \
    ac3 = __builtin_amdgcn_mfma_f32_16x16x32_bf16(a2, wg[3][2], ac3, 0,0,0);   \
    ac0 = __builtin_amdgcn_mfma_f32_16x16x32_bf16(a3, wg[0][3], ac0, 0,0,0);   \
    ac1 = __builtin_amdgcn_mfma_f32_16x16x32_bf16(a3, wg[1][3], ac1, 0,0,0);   \
    ac2 = __builtin_amdgcn_mfma_f32_16x16x32_bf16(a3, wg[2][3], ac2, 0,0,0);   \
    ac3 = __builtin_amdgcn_mfma_f32_16x16x32_bf16(a3, wg[3][3], ac3, 0,0,0);   \
    ac0 = __builtin_amdgcn_mfma_f32_16x16x32_bf16(a4, wg[0][4], ac0, 0,0,0);   \
    ac1 = __builtin_amdgcn_mfma_f32_16x16x32_bf16(a4, wg[1][4], ac1, 0,0,0);   \
    ac2 = __builtin_amdgcn_mfma_f32_16x16x32_bf16(a4, wg[2][4], ac2, 0,0,0);   \
    ac3 = __builtin_amdgcn_mfma_f32_16x16x32_bf16(a4, wg[3][4], ac3, 0,0,0);   \
    ac0 = __builtin_amdgcn_mfma_f32_16x16x32_bf16(a5, wg[0][5], ac0, 0,0,0);   \
    ac1 = __builtin_amdgcn_mfma_f32_16x16x32_bf16(a5, wg[1][5], ac1, 0,0,0);   \
    ac2 = __builtin_amdgcn_mfma_f32_16x16x32_bf16(a5, wg[2][5], ac2, 0,0,0);   \
    ac3 = __builtin_amdgcn_mfma_f32_16x16x32_bf16(a5, wg[3][5], ac3, 0,0,0);   \
    const float g0 = ac0[0] + bias[0];                                         \
    const float g1 = ac1[0] + bias[1];                                         \
    const float g2 = ac2[0] + bias[2];                                         \
    const float g3 = ac3[0] + bias[3];                                         \
    const float si = 1.f / (1.f + __expf(-g0));                                \
    const float sf = 1.f / (1.f + __expf(-g1));                                \
    const float tg = 1.f - 2.f / (__expf(2.f * g2) + 1.f);                     \
    const float so = 1.f / (1.f + __expf(-g3));                                \
    const float cn = sf * c + si * tg;                                         \
    const float tc = 1.f - 2.f / (__expf(2.f * cn) + 1.f);                     \
    const float hn = so * tc;                                                  \
    const int nxt_ = cur ^ 1;                                                  \
    if (s_ < P_my) { c = cn; zbuf[nxt_][(4*lq)*ZP + 64 + unit] = f2bf(hn); }   \
    if (w4 && (s_ + 1 < AV_x)) zbuf[nxt_][(4*w)*ZP + l] = f2bf(XNEXT);         \
    cur = nxt_;                                                                \
  } while (0)

    // ============ PHASE 1 step: 2-barrier mixed (+ catch-up pred) ===========
#define DO_STEP(S, XNEXT)                                                      \
  do {                                                                         \
    const int s_ = (S);                                                        \
    bar_lds();                                          /* B1: buf[cur] */     \
    const unsigned short* zc_ = zbuf[cur];                                     \
    bf16x8 a0 = *(const bf16x8*)(zc_ + abase +   0);                           \
    bf16x8 a1 = *(const bf16x8*)(zc_ + abase +  32);                           \
    bf16x8 a2 = *(const bf16x8*)(zc_ + abase +  64);                           \
    bf16x8 a3 = *(const bf16x8*)(zc_ + abase +  96);                           \
    bf16x8 a4 = *(const bf16x8*)(zc_ + abase + 128);                           \
    bf16x8 a5 = *(const bf16x8*)(zc_ + abase + 160);                           \
    if (w4 && s_ >= 1) {                 /* catch-up pred_{s-1} (dup-safe) */  \
      f32x4 ca = {0.f,0.f,0.f,0.f}, cb = {0.f,0.f,0.f,0.f};                    \
      ca = __builtin_amdgcn_mfma_f32_16x16x32_bf16(a2, wd0, ca, 0,0,0);        \
      cb = __builtin_amdgcn_mfma_f32_16x16x32_bf16(a4, wd2, cb, 0,0,0);        \
      ca = __builtin_amdgcn_mfma_f32_16x16x32_bf16(a3, wd1, ca, 0,0,0);        \
      cb = __builtin_amdgcn_mfma_f32_16x16x32_bf16(a5, wd3, cb, 0,0,0);        \
      if ((s_ - 1) < P_my) outb[(size_t)(s_-1) * OUTS] = ca[0] + cb[0] + bden; \
    }                                                                          \
    f32x4 ac0 = {0.f,0.f,0.f,0.f}, ac1 = {0.f,0.f,0.f,0.f},                    \
          ac2 = {0.f,0.f,0.f,0.f}, ac3 = {0.f,0.f,0.f,0.f};                    \
    ac0 = __builtin_amdgcn_mfma_f32_16x16x32_bf16(a0, wg[0][0], ac0, 0,0,0);   \
    ac1 = __builtin_amdgcn_mfma_f32_16x16x32_bf16(a0, wg[1][0], ac1, 0,0,0);   \
    ac2 = __builtin_amdgcn_mfma_f32_16x16x32_bf16(a0, wg[2][0], ac2, 0,0,0);   \
    ac3 = __builtin_amdgcn_mfma_f32_16x16x32_bf16(a0, wg[3][0], ac3, 0,0,0);   \
    ac0 = __builtin_amdgcn_mfma_f32_16x16x32_bf16(a1, wg[0][1], ac0, 0,0,0);   \
    ac1 = __builtin_amdgcn_mfma_f32_16x16x32_bf16(a1, wg[1][1], ac1, 0,0,0);   \
    ac2 = __builtin_amdgcn_mfma_f32_16x16x32_bf16(a1, wg[2][1], ac2, 0,0,0);   \
    ac3 = __builtin_amdgcn_mfma_f32_16x16x32_bf16(a1, wg[3][1], ac3, 0,0,0);   \
    ac0 = __builtin_amdgcn_mfma_f32_16x16x32_bf16(a2, wg[0][2], ac0, 0,0,0);   \
    ac1 = __builtin_amdgcn_mfma_f32_16x16x32_bf16(a2, wg[1][2], ac1, 0,0,0);   \
    ac2 = __builtin_amdgcn_mfma_f32_16x16x32_bf16(a2, wg[2][2], ac2, 0,0,0);   \
    ac3 = __builtin_amdgcn_mfma_f32_16x16x32_bf16(a2, wg[3][2], ac3, 0,0,0);   \
    ac0 = __builtin_amdgcn_mfma_f32_16x16x32_bf16(a3, wg[0][3], ac0, 0,0,0);   \
    ac1 = __builtin_amdgcn_mfma_f32_16x16x32_bf16(a3, wg[1][3], ac1, 0,0,0);   \
    ac2 = __builtin_amdgcn_mfma_f32_16x16x32_bf16(a3, wg[2][3], ac2, 0,0,0);   \
    ac3 = __builtin_amdgcn_mfma_f32_16x16x32_bf16(a3, wg[3][3], ac3, 0,0,0);   \
    ac0 = __builtin_amdgcn_mfma_f32_16x16x32_bf16(a4, wg[0][4], ac0, 0,0,0);   \
    ac1 = __builtin_amdgcn_mfma_f32_16x16x32_bf16(a4, wg[1][4], ac1, 0,0,0);   \
    ac2 = __builtin_amdgcn_mfma_f32_16x16x32_bf16(a4, wg[2][4], ac2, 0,0,0);   \
    ac3 = __builtin_amdgcn_mfma_f32_16x16x32_bf16(a4, wg[3][4], ac3, 0,0,0);   \
    ac0 = __builtin_amdgcn_mfma_f32_16x16x32_bf16(a5, wg[0][5], ac0, 0,0,0);   \
    ac1 = __builtin_amdgcn_mfma_f32_16x16x32_bf16(a5, wg[1][5], ac1, 0,0,0);   \
    ac2 = __builtin_amdgcn_mfma_f32_16x16x32_bf16(a5, wg[2][5], ac2, 0,0,0);   \
    ac3 = __builtin_amdgcn_mfma_f32_16x16x32_bf16(a5, wg[3][5], ac3, 0,0,0);   \
    const float g0 = ac0[0] + bias[0];                                         \
    const float g1 = ac1[0] + bias[1];                                         \
    const float g2 = ac2[0] + bias[2];                                         \
    const float g3 = ac3[0] + bias[3];                                         \
    const float si = 1.f / (1.f + __expf(-g0));                                \
    const float sf = 1.f / (1.f + __expf(-g1));                                \
    const float tg = 1.f - 2.f / (__expf(2.f * g2) + 1.f);                     \
    const float so = 1.f / (1.f + __expf(-g3));                                \
    const float cn = sf * c + si * tg;                                         \
    const float tc = 1.f - 2.f / (__expf(2.f * cn) + 1.f);                     \
    const float hn = so * tc;                                                  \
    const int nxt_ = cur ^ 1;                                                  \
    if (s_ < P_my) { c = cn; zbuf[nxt_][(4*lq)*ZP + 64 + unit] = f2bf(hn); }   \
    bar_lds();                                          /* B2: h ready */      \
    if (w4) {                                                                  \
      const unsigned short* zn_ = zbuf[nxt_];                                  \
      bf16x8 h0f = *(const bf16x8*)(zn_ + abase + 64 +  0);                    \
      bf16x8 h1f = *(const bf16x8*)(zn_ + abase + 64 + 32);                    \
      bf16x8 h2f = *(const bf16x8*)(zn_ + abase + 64 + 64);                    \
      bf16x8 h3f = *(const bf16x8*)(zn_ + abase + 64 + 96);                    \
      f32x4 pa = {0.f,0.f,0.f,0.f}, pb = {0.f,0.f,0.f,0.f};                    \
      pa = __builtin_amdgcn_mfma_f32_16x16x32_bf16(h0f, wd0, pa, 0,0,0);       \
      pb = __builtin_amdgcn_mfma_f32_16x16x32_bf16(h2f, wd2, pb, 0,0,0);       \
      pa = __builtin_amdgcn_mfma_f32_16x16x32_bf16(h1f, wd1, pa, 0,0,0);       \
      pb = __builtin_amdgcn_mfma_f32_16x16x32_bf16(h3f, wd3, pb, 0,0,0);       \
      const float pred_ = pa[0] + pb[0] + bden;                                \
      if (s_ < P_my) {                                                         \
        outb[(size_t)s_ * OUTS] = pred_;                                       \
        if (s_ + 1 >= AV_my)                                                   \
          zbuf[nxt_][(4*lq)*ZP + 16*w + l16] = f2bf(pred_);                    \
      }                                                                        \
      if (s_ + 1 < AV_x) zbuf[nxt_][(4*w)*ZP + l] = f2bf(XNEXT);               \
    }                                                                          \
    cur = nxt_;                                                                \
  } while (0)

    int t4 = 0;
    for (; t4 + 4 <= ph1s; t4 += 4) {                  // phase 0 (quad x)
        float4 qn = {0.f,0.f,0.f,0.f};
        if (w4 && (t4 + 4 < AV_x))
            qn = *(const float4*)(x + xbase + t4 + 4);
        DO_T(t4 + 0, qc.y);
        DO_T(t4 + 1, qc.z);
        DO_T(t4 + 2, qc.w);
        DO_T(t4 + 3, qn.x);
        qc = qn;
    }
    for (; t4 < ph1s; ++t4) {                          // phase 0 remainder
        float xs = 0.f;
        if (w4 && (t4 + 1 < AV_x)) xs = x[xbase + t4 + 1];
        DO_T(t4, xs);
    }
    for (; t4 < tsw; ++t4) {                           // phase 1 (short)
        float xs = 0.f;
        if (w4 && (t4 + 1 < AV_x)) xs = x[xbase + t4 + 1];
        DO_STEP(t4, xs);
    }
#undef DO_T
#undef DO_STEP

    // ============ PHASE 2: t in [tsw, maxP) — all rows auto (fold) ==========
    if (tsw < maxP) {
        const float* wfold = ws;
        const float* bfold = ws + 4*HH*HH;
        #pragma unroll
        for (int g = 0; g < 4; ++g) {
            const int n = 128*g + 16*w + l16;
            const float* rhh = W_hh + n * HH;
            const float* rfo = wfold + n * HH;
            #pragma unroll
            for (int j = 0; j < 4; ++j) {
                const int k = 32*j + 8*lq;
                bf16x8 r;
                #pragma unroll
                for (int i = 0; i < 8; i++) r[i] = (short)f2bf(rhh[k+i] + rfo[k+i]);
                wg[g][j] = r;
            }
            bias[g] += bfold[n];
        }

        for (int t = tsw; t < maxP; ++t) {
            bar_lds();                                 // single barrier
            const unsigned short* zc = zbuf[cur];
            bf16x8 h0f = *(const bf16x8*)(zc + abase + 64 +  0);
            bf16x8 h1f = *(const bf16x8*)(zc + abase + 64 + 32);
            bf16x8 h2f = *(const bf16x8*)(zc + abase + 64 + 64);
            bf16x8 h3f = *(const bf16x8*)(zc + abase + 64 + 96);

            if (w4) {                                  // deferred pred_{t-1}
                f32x4 pa = {0.f,0.f,0.f,0.f}, pb = {0.f,0.f,0.f,0.f};
                pa = __builtin_amdgcn_mfma_f32_16x16x32_bf16(h0f, wd0, pa, 0,0,0);
                pb = __builtin_amdgcn_mfma_f32_16x16x32_bf16(h2f, wd2, pb, 0,0,0);
                pa = __builtin_amdgcn_mfma_f32_16x16x32_bf16(h1f, wd1, pa, 0,0,0);
                pb = __builtin_amdgcn_mfma_f32_16x16x32_bf16(h3f, wd3, pb, 0,0,0);
                if ((t - 1) < P_my)                    // dup store at t=tsw is bit-identical
                    outb[(size_t)(t-1) * OUTS] = pa[0] + pb[0] + bden;
            }

            f32x4 ac0 = {0.f,0.f,0.f,0.f}, ac1 = {0.f,0.f,0.f,0.f},
                  ac2 = {0.f,0.f,0.f,0.f}, ac3 = {0.f,0.f,0.f,0.f};
            ac0 = __builtin_amdgcn_mfma_f32_16x16x32_bf16(h0f, wg[0][0], ac0, 0,0,0);
            ac1 = __builtin_amdgcn_mfma_f32_16x16x32_bf16(h0f, wg[1][0], ac1, 0,0,0);
            ac2 = __builtin_amdgcn_mfma_f32_16x16x32_bf16(h0f, wg[2][0], ac2, 0,0,0);
            ac3 = __builtin_amdgcn_mfma_f32_16x16x32_bf16(h0f, wg[3][0], ac3, 0,0,0);
            ac0 = __builtin_amdgcn_mfma_f32_16x16x32_bf16(h1f, wg[0][1], ac0, 0,0,0);
            ac1 = __builtin_amdgcn_mfma_f32_16x16x32_bf16(h1f, wg[1][1], ac1, 0,0,0);
            ac2 = __builtin_amdgcn_mfma_f32_16x16x32_bf16(h1f, wg[2][1], ac2, 0,0,0);
            ac3 = __builtin_amdgcn_mfma_f32_16x16x32_bf16(h1f, wg[3][1], ac3, 0,0,0);
            ac0 = __builtin_amdgcn_mfma_f32_16x16x32_bf16(h2f, wg[0][2], ac0, 0,0,0);
            ac1 = __builtin_amdgcn_mfma_f32_16x16x32_bf16(h2f, wg[1][2], ac1, 0,0,0);
            ac2 = __builtin_amdgcn_mfma_f32_16x16x32_bf16(h2f, wg[2][2], ac2, 0,0,0);
            ac3 = __builtin_amdgcn_mfma_f32_16x16x32_bf16(h2f, wg[3][2], ac3, 0,0,0);
            ac0 = __builtin_amdgcn_mfma_f32_16x16x32_bf16(h3f, wg[0][3], ac0, 0,0,0);
            ac1 = __builtin_amdgcn_mfma_f32_16x16x32_bf16(h3f, wg[1][3], ac1, 0,0,0);
            ac2 = __builtin_amdgcn_mfma_f32_16x16x32_bf16(h3f, wg[2][3], ac2, 0,0,0);
            ac3 = __builtin_amdgcn_mfma_f32_16x16x32_bf16(h3f, wg[3][3], ac3, 0,0,0);

            const float g0 = ac0[0] + bias[0];
            const float g1 = ac1[0] + bias[1];
            const float g2 = ac2[0] + bias[2];
            const float g3 = ac3[0] + bias[3];
            const float si = 1.f / (1.f + __expf(-g0));
            const float sf = 1.f / (1.f + __expf(-g1));
            const float tg = 1.f - 2.f / (__expf(2.f * g2) + 1.f);
            const float so = 1.f / (1.f + __expf(-g3));
            const float cn = sf * c + si * tg;
            const float tc = 1.f - 2.f / (__expf(2.f * cn) + 1.f);
            const float hn = so * tc;

            const int nxt = cur ^ 1;
            if (t < P_my) { c = cn; zbuf[nxt][(4*lq)*ZP + 64 + unit] = f2bf(hn); }
            cur = nxt;
        }

        // epilogue: pred_{maxP-1} from h_{maxP}
        bar_lds();
        if (w4) {
            const unsigned short* zc = zbuf[cur];
            bf16x8 h0f = *(const bf16x8*)(zc + abase + 64 +  0);
            bf16x8 h1f = *(const bf16x8*)(zc + abase + 64 + 32);
            bf16x8 h2f = *(const bf16x8*)(zc + abase + 64 + 64);
            bf16x8 h3f = *(const bf16x8*)(zc + abase + 64 + 96);
            f32x4 pa = {0.f,0.f,0.f,0.f}, pb = {0.f,0.f,0.f,0.f};
            pa = __builtin_amdgcn_mfma_f32_16x16x32_bf16(h0f, wd0, pa, 0,0,0);
            pb = __builtin_amdgcn_mfma_f32_16x16x32_bf16(h2f, wd2, pb, 0,0,0);
            pa = __builtin_amdgcn_mfma_f32_16x16x32_bf16(h1f, wd1, pa, 0,0,0);
            pb = __builtin_amdgcn_mfma_f32_16x16x32_bf16(h3f, wd3, pb, 0,0,0);
            if ((maxP - 1) < P_my)
                outb[(size_t)(maxP-1) * OUTS] = pa[0] + pb[0] + bden;
        }
    }

    // ============ MERGED TAIL: out[t][r][f] = x[r][f][t] for t >= P_r =======
    // Block-uniform loops (rows and P are scalars); LDS transpose per 64-t
    // chunk; 512 threads: load tt-coalesced, store f-coalesced.
    #pragma unroll 1
    for (int q = 0; q < 4; ++q) {
        const int r = perm[b0 + q];
        const int P = predict_len[r];
        if (P >= SS) continue;
        const float* xr = x + (size_t)r * FF * SS;
        for (int t0 = (P >> 6) << 6; t0 < SS; t0 += 64) {
            bar_lds();                                 // tile reusable
            {
                const int tt = tid & 63;
                const int fb = tid >> 6;               // 0..7
                #pragma unroll
                for (int i = 0; i < 8; ++i) {
                    const int f = fb * 8 + i;
                    tile[f][tt] = xr[(size_t)f * SS + t0 + tt];
                }
            }
            bar_lds();                                 // tile filled
            {
                const int f2 = tid & 63;
                const int tb = tid >> 6;               // 0..7
                #pragma unroll
                for (int i = 0; i < 8; ++i) {
                    const int tloc = tb * 8 + i;
                    const int t = t0 + tloc;
                    if (t >= P)
                        out[(size_t)t * OUTS + (size_t)r * FF + f2] = tile[f2][tloc];
                }
            }
        }
    }
}

extern "C" void kernel_launch(void* const* d_in, const int* in_sizes, int n_in,
                              void* d_out, int out_size, void* d_ws, size_t ws_size,
                              hipStream_t stream) {
    const float* x       = (const float*)d_in[0];
    const int*   avail   = (const int*)  d_in[1];
    const int*   plen    = (const int*)  d_in[2];
    const float* W_ih    = (const float*)d_in[3];
    const float* W_hh    = (const float*)d_in[4];
    const float* b_ih    = (const float*)d_in[5];
    const float* b_hh    = (const float*)d_in[6];
    const float* W_den   = (const float*)d_in[7];
    const float* b_den   = (const float*)d_in[8];
    const float* init_ch = (const float*)d_in[9];
    float*       out     = (float*)d_out;
    float*       ws      = (float*)d_ws;       // 264KB fold + 4KB perm
    int*         perm    = (int*)(ws + 4*HH*HH + 4*HH);

    fold_kernel<<<dim3(4*HH), dim3(HH), 0, stream>>>(W_ih, W_den, b_den, ws);
    sort_kernel<<<dim3(4), dim3(256), 0, stream>>>(avail, perm);
    lstm_mfma_kernel<<<dim3(BB/4), dim3(512), 0, stream>>>(
        x, avail, plen, W_ih, W_hh, b_ih, b_hh, W_den, b_den, init_ch, ws, perm, out);
}

// Round 15
// 418.522 us; speedup vs baseline: 1.3613x; 1.0498x over previous
//
#include <hip/hip_runtime.h>

#define BB 1024
#define FF 64
#define SS 512
#define HH 128
#define ZP 200          // z row pitch in bf16 elems (192 data + 8 pad)
#define ZROWS 16
#define OUTS (BB*FF)

typedef __attribute__((ext_vector_type(8))) short bf16x8;
typedef __attribute__((ext_vector_type(4))) float f32x4;

__device__ __forceinline__ unsigned short f2bf(float f) {
    unsigned int u = __float_as_uint(f);
    u += 0x7fff + ((u >> 16) & 1);          // RNE
    return (unsigned short)(u >> 16);
}

// LDS-only barrier: fused waitcnt+s_barrier under one "memory" clobber;
// sched_barrier(0) fences the machine scheduler on both sides (rule #18).
__device__ __forceinline__ void bar_lds() {
    __builtin_amdgcn_sched_barrier(0);
    asm volatile("s_waitcnt lgkmcnt(0)\n\ts_barrier" ::: "memory");
    __builtin_amdgcn_sched_barrier(0);
}

// ---------------------------------------------------------------------------
// Fold kernel: W_fold[n][k] = sum_f W_ih[n][f]*W_den[f][k],
// b_fold[n]   = sum_f W_ih[n][f]*b_den[f].
// ws floats: [0,65536) W_fold, [65536,66048) b_fold; ints at 66560: perm.
// ---------------------------------------------------------------------------
__global__ void fold_kernel(const float* __restrict__ W_ih,
                            const float* __restrict__ W_den,
                            const float* __restrict__ b_den,
                            float* __restrict__ ws)
{
    const int n = blockIdx.x;      // 512
    const int k = threadIdx.x;     // 128
    float s = 0.f;
    #pragma unroll 8
    for (int f = 0; f < FF; ++f) s = fmaf(W_ih[n*FF + f], W_den[f*HH + k], s);
    ws[n*HH + k] = s;
    if (k == 0) {
        float bsum = 0.f;
        #pragma unroll 8
        for (int f = 0; f < FF; ++f) bsum = fmaf(W_ih[n*FF + f], b_den[f], bsum);
        ws[4*HH*HH + n] = bsum;
    }
}

// ---------------------------------------------------------------------------
// Rank-sort rows by available_len (LDS-staged, parallel: 4 blocks x 256).
// perm[rank] = row; deterministic tie-break by index.
// ---------------------------------------------------------------------------
__global__ void sort_kernel(const int* __restrict__ avail, int* __restrict__ perm)
{
    __shared__ int keys[BB];
    const int t = threadIdx.x;
    for (int i = t; i < BB; i += 256) keys[i] = avail[i];
    __syncthreads();
    const int i = blockIdx.x * 256 + t;
    const int key = keys[i];
    int rank = 0;
    #pragma unroll 8
    for (int j = 0; j < BB; ++j) {
        const int kj = keys[j];
        rank += (kj < key) || (kj == key && j < i);
    }
    perm[rank] = i;
}

// ---------------------------------------------------------------------------
// Main recurrence (r14 structure; WAVE-ROLE REBALANCE):
//   waves 0-3: x global-load + x_hat ds_write (producer half)
//   waves 4-7: pred MFMAs + out-store + feedback ds_write (consumer half)
// Previously both roles sat on waves 0-3 -> barrier skew; waves 4-7 idled.
// 256 blocks x 512 threads; block owns 4 AV-SORTED rows at M-rows {0,4,8,12}.
// PHASE 0 [0,minAV-1): teacher, 1 barrier, pred deferred 1 step.
// PHASE 1 [minAV-1,maxAV): 2-barrier mixed (feedback at B2), ~1-3 steps.
// PHASE 2 [maxAV,maxP): W_auto fold, 1 barrier, deferred pred.
// EPILOGUE: merged tail transpose (t >= P) per block.
// ---------------------------------------------------------------------------
__global__ __launch_bounds__(512)
void lstm_mfma_kernel(const float* __restrict__ x,
                      const int* __restrict__ available_len,
                      const int* __restrict__ predict_len,
                      const float* __restrict__ W_ih,
                      const float* __restrict__ W_hh,
                      const float* __restrict__ b_ih,
                      const float* __restrict__ b_hh,
                      const float* __restrict__ W_den,
                      const float* __restrict__ b_den,
                      const float* __restrict__ init_ch,
                      const float* __restrict__ ws,
                      const int* __restrict__ perm,
                      float* __restrict__ out)
{
    const int b0  = blockIdx.x * 4;
    const int tid = threadIdx.x;
    const int w   = tid >> 6;          // wave 0..7
    const int l   = tid & 63;
    const int l16 = l & 15;
    const int lq  = l >> 4;            // 0..3
    const bool w4    = (w < 4);        // x-duty half
    const bool predw = (w >= 4);       // pred-duty half
    const int  wp    = w & 3;          // pred feature group

    __shared__ __align__(16) unsigned short zbuf[2][ZROWS * ZP];
    __shared__ float tile[64][65];     // tail-transpose scratch

    for (int i = tid; i < 2 * ZROWS * ZP / 2; i += 512)
        ((unsigned int*)zbuf)[i] = 0u;

    const int rr0 = perm[b0], rr1 = perm[b0+1], rr2 = perm[b0+2], rr3 = perm[b0+3];
    const int p0 = predict_len[rr0], p1 = predict_len[rr1],
              p2 = predict_len[rr2], p3 = predict_len[rr3];
    const int a0i = available_len[rr0], a1i = available_len[rr1],
              a2i = available_len[rr2], a3i = available_len[rr3];
    const int maxP  = max(max(p0, p1), max(p2, p3));
    const int tsw   = max(max(a0i, a1i), max(a2i, a3i));   // phase-2 start
    const int tmin  = min(min(a0i, a1i), min(a2i, a3i));
    const int ph1s  = (tmin > 1) ? (tmin - 1) : 0;         // phase-1 start
    const int rl    = perm[b0 + lq];            // lane's row
    const int P_my  = predict_len[rl];
    const int AV_my = available_len[rl];

    // ---- gate weights: wg[gate][ktile 0..5], bf16, register-resident ----
    bf16x8 wg[4][6];
    float bias[4];
    #pragma unroll
    for (int g = 0; g < 4; ++g) {
        const int n = 128*g + 16*w + l16;
        const float* rih = W_ih + n * FF;
        const float* rhh = W_hh + n * HH;
        #pragma unroll
        for (int kt = 0; kt < 6; ++kt) {
            const int k = 32*kt + 8*lq;
            const float* src = (k < 64) ? (rih + k) : (rhh + (k - 64));
            bf16x8 r;
            #pragma unroll
            for (int i = 0; i < 8; i++) r[i] = (short)f2bf(src[i]);
            wg[g][kt] = r;
        }
        bias[g] = b_ih[n] + b_hh[n];
    }

    // pred weights (waves 4-7): f = 16*wp + l16
    bf16x8 wd0, wd1, wd2, wd3;
    float bden = 0.f;
    if (predw) {
        const int f = 16*wp + l16;
        const float* rd = W_den + f * HH;
        bf16x8 r;
        #pragma unroll
        for (int i = 0; i < 8; i++) r[i] = (short)f2bf(rd[0*32 + 8*lq + i]);
        wd0 = r;
        #pragma unroll
        for (int i = 0; i < 8; i++) r[i] = (short)f2bf(rd[1*32 + 8*lq + i]);
        wd1 = r;
        #pragma unroll
        for (int i = 0; i < 8; i++) r[i] = (short)f2bf(rd[2*32 + 8*lq + i]);
        wd2 = r;
        #pragma unroll
        for (int i = 0; i < 8; i++) r[i] = (short)f2bf(rd[3*32 + 8*lq + i]);
        wd3 = r;
        bden = b_den[f];
    }

    // x duty (waves 0-3): stream sorted row perm[b0+w], feature l
    size_t xbase = 0;
    int AV_x = 0;
    if (w4) {
        const int rx = perm[b0 + w];
        xbase = ((size_t)rx * FF + l) * SS;
        AV_x  = available_len[rx];
    }

    const int unit  = 16*w + l16;
    const int abase = l16*ZP + 8*lq;
    float c = init_ch[unit];
    const float h0v = init_ch[HH + unit];
    float* outb = out + (size_t)rl * FF + 16*wp + l16;   // valid for predw

    bar_lds();                          // zeroing visible before init writes

    zbuf[0][(4*lq)*ZP + 64 + unit] = f2bf(h0v);
    if (w4) zbuf[0][(4*w)*ZP + l] = f2bf(x[xbase]);

    float4 qc = {0.f,0.f,0.f,0.f};
    if (AV_x > 1) qc = *(const float4*)(x + xbase);   // x_0..x_3

    int cur = 0;

    // ============ PHASE 0: t in [0, ph1s) — pure teacher, 1 barrier =========
#define DO_T(S, XNEXT)                                                         \
  do {                                                                         \
    const int s_ = (S);                                                        \
    bar_lds();                                          /* single barrier */   \
    const unsigned short* zc_ = zbuf[cur];                                     \
    bf16x8 a0 = *(const bf16x8*)(zc_ + abase +   0);                           \
    bf16x8 a1 = *(const bf16x8*)(zc_ + abase +  32);                           \
    bf16x8 a2 = *(const bf16x8*)(zc_ + abase +  64);                           \
    bf16x8 a3 = *(const bf16x8*)(zc_ + abase +  96);                           \
    bf16x8 a4 = *(const bf16x8*)(zc_ + abase + 128);                           \
    bf16x8 a5 = *(const bf16x8*)(zc_ + abase + 160);                           \
    if (predw && s_ >= 1) {              /* deferred pred_{s-1} = Wden.h_s */  \
      f32x4 ca = {0.f,0.f,0.f,0.f}, cb = {0.f,0.f,0.f,0.f};                    \
      ca = __builtin_amdgcn_mfma_f32_16x16x32_bf16(a2, wd0, ca, 0,0,0);        \
      cb = __builtin_amdgcn_mfma_f32_16x16x32_bf16(a4, wd2, cb, 0,0,0);        \
      ca = __builtin_amdgcn_mfma_f32_16x16x32_bf16(a3, wd1, ca, 0,0,0);        \
      cb = __builtin_amdgcn_mfma_f32_16x16x32_bf16(a5, wd3, cb, 0,0,0);        \
      if ((s_ - 1) < P_my) outb[(size_t)(s_-1) * OUTS] = ca[0] + cb[0] + bden; \
    }                                                                          \
    f32x4 ac0 = {0.f,0.f,0.f,0.f}, ac1 = {0.f,0.f,0.f,0.f},                    \
          ac2 = {0.f,0.f,0.f,0.f}, ac3 = {0.f,0.f,0.f,0.f};                    \
    ac0 = __builtin_amdgcn_mfma_f32_16x16x32_bf16(a0, wg[0][0], ac0, 0,0,0);   \
    ac1 = __builtin_amdgcn_mfma_f32_16x16x32_bf16(a0, wg[1][0], ac1, 0,0,0);   \
    ac2 = __builtin_amdgcn_mfma_f32_16x16x32_bf16(a0, wg[2][0], ac2, 0,0,0);   \
    ac3 = __builtin_amdgcn_mfma_f32_16x16x32_bf16(a0, wg[3][0], ac3, 0,0,0);   \
    ac0 = __builtin_amdgcn_mfma_f32_16x16x32_bf16(a1, wg[0][1], ac0, 0,0,0);   \
    ac1 = __builtin_amdgcn_mfma_f32_16x16x32_bf16(a1, wg[1][1], ac1, 0,0,0);   \
    ac2 = __builtin_amdgcn_mfma_f32_16x16x32_bf16(a1, wg[2][1], ac2, 0,0,0);   \
    ac3 = __builtin_amdgcn_mfma_f32_16x16x32_bf16(a1, wg[3][1], ac3, 0,0,0);   \
    ac0 = __builtin_amdgcn_mfma_f32_16x16x32_bf16(a2, wg[0][2], ac0, 0,0,0);   \
    ac1 = __builtin_amdgcn_mfma_f32_16x16x32_bf16(a2, wg[1][2], ac1, 0,0,0);   \
    ac2 = __builtin_amdgcn_mfma_f32_16x16x32_bf16(a2, wg[2][2], ac2, 0,0,0);   \
    ac3 = __builtin_amdgcn_mfma_f32_16x16x32_bf16(a2, wg[3][2], ac3, 0,0,0);   \
    ac0 = __builtin_amdgcn_mfma_f32_16x16x32_bf16(a3, wg[0][3], ac0, 0,0,0);   \
    ac1 = __builtin_amdgcn_mfma_f32_16x16x32_bf16(a3, wg[1][3], ac1, 0,0,0);   \
    ac2 = __builtin_amdgcn_mfma_f32_16x16x32_bf16(a3, wg[2][3], ac2, 0,0,0);   \
    ac3 = __builtin_amdgcn_mfma_f32_16x16x32_bf16(a3, wg[3][3], ac3, 0,0,0);   \
    ac0 = __builtin_amdgcn_mfma_f32_16x16x32_bf16(a4, wg[0][4], ac0, 0,0,0);   \
    ac1 = __builtin_amdgcn_mfma_f32_16x16x32_bf16(a4, wg[1][4], ac1, 0,0,0);   \
    ac2 = __builtin_amdgcn_mfma_f32_16x16x32_bf16(a4, wg[2][4], ac2, 0,0,0);   \
    ac3 = __builtin_amdgcn_mfma_f32_16x16x32_bf16(a4, wg[3][4], ac3, 0,0,0);   \
    ac0 = __builtin_amdgcn_mfma_f32_16x16x32_bf16(a5, wg[0][5], ac0, 0,0,0);   \
    ac1 = __builtin_amdgcn_mfma_f32_16x16x32_bf16(a5, wg[1][5], ac1, 0,0,0);   \
    ac2 = __builtin_amdgcn_mfma_f32_16x16x32_bf16(a5, wg[2][5], ac2, 0,0,0);   \
    ac3 = __builtin_amdgcn_mfma_f32_16x16x32_bf16(a5, wg[3][5], ac3, 0,0,0);   \
    const float g0 = ac0[0] + bias[0];                                         \
    const float g1 = ac1[0] + bias[1];                                         \
    const float g2 = ac2[0] + bias[2];                                         \
    const float g3 = ac3[0] + bias[3];                                         \
    const float si = 1.f / (1.f + __expf(-g0));                                \
    const float sf = 1.f / (1.f + __expf(-g1));                                \
    const float tg = 1.f - 2.f / (__expf(2.f * g2) + 1.f);                     \
    const float so = 1.f / (1.f + __expf(-g3));                                \
    const float cn = sf * c + si * tg;                                         \
    const float tc = 1.f - 2.f / (__expf(2.f * cn) + 1.f);                     \
    const float hn = so * tc;                                                  \
    const int nxt_ = cur ^ 1;                                                  \
    if (s_ < P_my) { c = cn; zbuf[nxt_][(4*lq)*ZP + 64 + unit] = f2bf(hn); }   \
    if (w4 && (s_ + 1 < AV_x)) zbuf[nxt_][(4*w)*ZP + l] = f2bf(XNEXT);         \
    cur = nxt_;                                                                \
  } while (0)

    // ============ PHASE 1 step: 2-barrier mixed (+ catch-up pred) ===========
#define DO_STEP(S, XNEXT)                                                      \
  do {                                                                         \
    const int s_ = (S);                                                        \
    bar_lds();                                          /* B1: buf[cur] */     \
    const unsigned short* zc_ = zbuf[cur];                                     \
    bf16x8 a0 = *(const bf16x8*)(zc_ + abase +   0);                           \
    bf16x8 a1 = *(const bf16x8*)(zc_ + abase +  32);                           \
    bf16x8 a2 = *(const bf16x8*)(zc_ + abase +  64);                           \
    bf16x8 a3 = *(const bf16x8*)(zc_ + abase +  96);                           \
    bf16x8 a4 = *(const bf16x8*)(zc_ + abase + 128);                           \
    bf16x8 a5 = *(const bf16x8*)(zc_ + abase + 160);                           \
    if (predw && s_ >= 1) {              /* catch-up pred_{s-1} (dup-safe) */  \
      f32x4 ca = {0.f,0.f,0.f,0.f}, cb = {0.f,0.f,0.f,0.f};                    \
      ca = __builtin_amdgcn_mfma_f32_16x16x32_bf16(a2, wd0, ca, 0,0,0);        \
      cb = __builtin_amdgcn_mfma_f32_16x16x32_bf16(a4, wd2, cb, 0,0,0);        \
      ca = __builtin_amdgcn_mfma_f32_16x16x32_bf16(a3, wd1, ca, 0,0,0);        \
      cb = __builtin_amdgcn_mfma_f32_16x16x32_bf16(a5, wd3, cb, 0,0,0);        \
      if ((s_ - 1) < P_my) outb[(size_t)(s_-1) * OUTS] = ca[0] + cb[0] + bden; \
    }                                                                          \
    f32x4 ac0 = {0.f,0.f,0.f,0.f}, ac1 = {0.f,0.f,0.f,0.f},                    \
          ac2 = {0.f,0.f,0.f,0.f}, ac3 = {0.f,0.f,0.f,0.f};                    \
    ac0 = __builtin_amdgcn_mfma_f32_16x16x32_bf16(a0, wg[0][0], ac0, 0,0,0);   \
    ac1 = __builtin_amdgcn_mfma_f32_16x16x32_bf16(a0, wg[1][0], ac1, 0,0,0);   \
    ac2 = __builtin_amdgcn_mfma_f32_16x16x32_bf16(a0, wg[2][0], ac2, 0,0,0);   \
    ac3 = __builtin_amdgcn_mfma_f32_16x16x32_bf16(a0, wg[3][0], ac3, 0,0,0);   \
    ac0 = __builtin_amdgcn_mfma_f32_16x16x32_bf16(a1, wg[0][1], ac0, 0,0,0);   \
    ac1 = __builtin_amdgcn_mfma_f32_16x16x32_bf16(a1, wg[1][1], ac1, 0,0,0);   \
    ac2 = __builtin_amdgcn_mfma_f32_16x16x32_bf16(a1, wg[2][1], ac2, 0,0,0);   \
    ac3 = __builtin_amdgcn_mfma_f32_16x16x32_bf16(a1, wg[3][1], ac3, 0,0,0);   \
    ac0 = __builtin_amdgcn_mfma_f32_16x16x32_bf16(a2, wg[0][2], ac0, 0,0,0);   \
    ac1 = __builtin_amdgcn_mfma_f32_16x16x32_bf16(a2, wg[1][2], ac1, 0,0,0);   \
    ac2 = __builtin_amdgcn_mfma_f32_16x16x32_bf16(a2, wg[2][2], ac2, 0,0,0);   \
    ac3 = __builtin_amdgcn_mfma_f32_16x16x32_bf16(a2, wg[3][2], ac3, 0,0,0);   \
    ac0 = __builtin_amdgcn_mfma_f32_16x16x32_bf16(a3, wg[0][3], ac0, 0,0,0);   \
    ac1 = __builtin_amdgcn_mfma_f32_16x16x32_bf16(a3, wg[1][3], ac1, 0,0,0);   \
    ac2 = __builtin_amdgcn_mfma_f32_16x16x32_bf16(a3, wg[2][3], ac2, 0,0,0);   \
    ac3 = __builtin_amdgcn_mfma_f32_16x16x32_bf16(a3, wg[3][3], ac3, 0,0,0);   \
    ac0 = __builtin_amdgcn_mfma_f32_16x16x32_bf16(a4, wg[0][4], ac0, 0,0,0);   \
    ac1 = __builtin_amdgcn_mfma_f32_16x16x32_bf16(a4, wg[1][4], ac1, 0,0,0);   \
    ac2 = __builtin_amdgcn_mfma_f32_16x16x32_bf16(a4, wg[2][4], ac2, 0,0,0);   \
    ac3 = __builtin_amdgcn_mfma_f32_16x16x32_bf16(a4, wg[3][4], ac3, 0,0,0);   \
    ac0 = __builtin_amdgcn_mfma_f32_16x16x32_bf16(a5, wg[0][5], ac0, 0,0,0);   \
    ac1 = __builtin_amdgcn_mfma_f32_16x16x32_bf16(a5, wg[1][5], ac1, 0,0,0);   \
    ac2 = __builtin_amdgcn_mfma_f32_16x16x32_bf16(a5, wg[2][5], ac2, 0,0,0);   \
    ac3 = __builtin_amdgcn_mfma_f32_16x16x32_bf16(a5, wg[3][5], ac3, 0,0,0);   \
    const float g0 = ac0[0] + bias[0];                                         \
    const float g1 = ac1[0] + bias[1];                                         \
    const float g2 = ac2[0] + bias[2];                                         \
    const float g3 = ac3[0] + bias[3];                                         \
    const float si = 1.f / (1.f + __expf(-g0));                                \
    const float sf = 1.f / (1.f + __expf(-g1));                                \
    const float tg = 1.f - 2.f / (__expf(2.f * g2) + 1.f);                     \
    const float so = 1.f / (1.f + __expf(-g3));                                \
    const float cn = sf * c + si * tg;                                         \
    const float tc = 1.f - 2.f / (__expf(2.f * cn) + 1.f);                     \
    const float hn = so * tc;                                                  \
    const int nxt_ = cur ^ 1;                                                  \
    if (s_ < P_my) { c = cn; zbuf[nxt_][(4*lq)*ZP + 64 + unit] = f2bf(hn); }   \
    bar_lds();                                          /* B2: h ready */      \
    if (predw) {                                                               \
      const unsigned short* zn_ = zbuf[nxt_];                                  \
      bf16x8 h0f = *(const bf16x8*)(zn_ + abase + 64 +  0);                    \
      bf16x8 h1f = *(const bf16x8*)(zn_ + abase + 64 + 32);                    \
      bf16x8 h2f = *(const bf16x8*)(zn_ + abase + 64 + 64);                    \
      bf16x8 h3f = *(const bf16x8*)(zn_ + abase + 64 + 96);                    \
      f32x4 pa = {0.f,0.f,0.f,0.f}, pb = {0.f,0.f,0.f,0.f};                    \
      pa = __builtin_amdgcn_mfma_f32_16x16x32_bf16(h0f, wd0, pa, 0,0,0);       \
      pb = __builtin_amdgcn_mfma_f32_16x16x32_bf16(h2f, wd2, pb, 0,0,0);       \
      pa = __builtin_amdgcn_mfma_f32_16x16x32_bf16(h1f, wd1, pa, 0,0,0);       \
      pb = __builtin_amdgcn_mfma_f32_16x16x32_bf16(h3f, wd3, pb, 0,0,0);       \
      const float pred_ = pa[0] + pb[0] + bden;                                \
      if (s_ < P_my) {                                                         \
        outb[(size_t)s_ * OUTS] = pred_;                                       \
        if (s_ + 1 >= AV_my)                                                   \
          zbuf[nxt_][(4*lq)*ZP + 16*wp + l16] = f2bf(pred_);                   \
      }                                                                        \
    }                                                                          \
    if (w4 && (s_ + 1 < AV_x)) zbuf[nxt_][(4*w)*ZP + l] = f2bf(XNEXT);         \
    cur = nxt_;                                                                \
  } while (0)

    int t4 = 0;
    for (; t4 + 4 <= ph1s; t4 += 4) {                  // phase 0 (quad x)
        float4 qn = {0.f,0.f,0.f,0.f};
        if (w4 && (t4 + 4 < AV_x))
            qn = *(const float4*)(x + xbase + t4 + 4);
        DO_T(t4 + 0, qc.y);
        DO_T(t4 + 1, qc.z);
        DO_T(t4 + 2, qc.w);
        DO_T(t4 + 3, qn.x);
        qc = qn;
    }
    for (; t4 < ph1s; ++t4) {                          // phase 0 remainder
        float xs = 0.f;
        if (w4 && (t4 + 1 < AV_x)) xs = x[xbase + t4 + 1];
        DO_T(t4, xs);
    }
    for (; t4 < tsw; ++t4) {                           // phase 1 (short)
        float xs = 0.f;
        if (w4 && (t4 + 1 < AV_x)) xs = x[xbase + t4 + 1];
        DO_STEP(t4, xs);
    }
#undef DO_T
#undef DO_STEP

    // ============ PHASE 2: t in [tsw, maxP) — all rows auto (fold) ==========
    if (tsw < maxP) {
        const float* wfold = ws;
        const float* bfold = ws + 4*HH*HH;
        #pragma unroll
        for (int g = 0; g < 4; ++g) {
            const int n = 128*g + 16*w + l16;
            const float* rhh = W_hh + n * HH;
            const float* rfo = wfold + n * HH;
            #pragma unroll
            for (int j = 0; j < 4; ++j) {
                const int k = 32*j + 8*lq;
                bf16x8 r;
                #pragma unroll
                for (int i = 0; i < 8; i++) r[i] = (short)f2bf(rhh[k+i] + rfo[k+i]);
                wg[g][j] = r;
            }
            bias[g] += bfold[n];
        }

        for (int t = tsw; t < maxP; ++t) {
            bar_lds();                                 // single barrier
            const unsigned short* zc = zbuf[cur];
            bf16x8 h0f = *(const bf16x8*)(zc + abase + 64 +  0);
            bf16x8 h1f = *(const bf16x8*)(zc + abase + 64 + 32);
            bf16x8 h2f = *(const bf16x8*)(zc + abase + 64 + 64);
            bf16x8 h3f = *(const bf16x8*)(zc + abase + 64 + 96);

            if (predw) {                               // deferred pred_{t-1}
                f32x4 pa = {0.f,0.f,0.f,0.f}, pb = {0.f,0.f,0.f,0.f};
                pa = __builtin_amdgcn_mfma_f32_16x16x32_bf16(h0f, wd0, pa, 0,0,0);
                pb = __builtin_amdgcn_mfma_f32_16x16x32_bf16(h2f, wd2, pb, 0,0,0);
                pa = __builtin_amdgcn_mfma_f32_16x16x32_bf16(h1f, wd1, pa, 0,0,0);
                pb = __builtin_amdgcn_mfma_f32_16x16x32_bf16(h3f, wd3, pb, 0,0,0);
                if ((t - 1) < P_my)                    // dup store at t=tsw is bit-identical
                    outb[(size_t)(t-1) * OUTS] = pa[0] + pb[0] + bden;
            }

            f32x4 ac0 = {0.f,0.f,0.f,0.f}, ac1 = {0.f,0.f,0.f,0.f},
                  ac2 = {0.f,0.f,0.f,0.f}, ac3 = {0.f,0.f,0.f,0.f};
            ac0 = __builtin_amdgcn_mfma_f32_16x16x32_bf16(h0f, wg[0][0], ac0, 0,0,0);
            ac1 = __builtin_amdgcn_mfma_f32_16x16x32_bf16(h0f, wg[1][0], ac1, 0,0,0);
            ac2 = __builtin_amdgcn_mfma_f32_16x16x32_bf16(h0f, wg[2][0], ac2, 0,0,0);
            ac3 = __builtin_amdgcn_mfma_f32_16x16x32_bf16(h0f, wg[3][0], ac3, 0,0,0);
            ac0 = __builtin_amdgcn_mfma_f32_16x16x32_bf16(h1f, wg[0][1], ac0, 0,0,0);
            ac1 = __builtin_amdgcn_mfma_f32_16x16x32_bf16(h1f, wg[1][1], ac1, 0,0,0);
            ac2 = __builtin_amdgcn_mfma_f32_16x16x32_bf16(h1f, wg[2][1], ac2, 0,0,0);
            ac3 = __builtin_amdgcn_mfma_f32_16x16x32_bf16(h1f, wg[3][1], ac3, 0,0,0);
            ac0 = __builtin_amdgcn_mfma_f32_16x16x32_bf16(h2f, wg[0][2], ac0, 0,0,0);
            ac1 = __builtin_amdgcn_mfma_f32_16x16x32_bf16(h2f, wg[1][2], ac1, 0,0,0);
            ac2 = __builtin_amdgcn_mfma_f32_16x16x32_bf16(h2f, wg[2][2], ac2, 0,0,0);
            ac3 = __builtin_amdgcn_mfma_f32_16x16x32_bf16(h2f, wg[3][2], ac3, 0,0,0);
            ac0 = __builtin_amdgcn_mfma_f32_16x16x32_bf16(h3f, wg[0][3], ac0, 0,0,0);
            ac1 = __builtin_amdgcn_mfma_f32_16x16x32_bf16(h3f, wg[1][3], ac1, 0,0,0);
            ac2 = __builtin_amdgcn_mfma_f32_16x16x32_bf16(h3f, wg[2][3], ac2, 0,0,0);
            ac3 = __builtin_amdgcn_mfma_f32_16x16x32_bf16(h3f, wg[3][3], ac3, 0,0,0);

            const float g0 = ac0[0] + bias[0];
            const float g1 = ac1[0] + bias[1];
            const float g2 = ac2[0] + bias[2];
            const float g3 = ac3[0] + bias[3];
            const float si = 1.f / (1.f + __expf(-g0));
            const float sf = 1.f / (1.f + __expf(-g1));
            const float tg = 1.f - 2.f / (__expf(2.f * g2) + 1.f);
            const float so = 1.f / (1.f + __expf(-g3));
            const float cn = sf * c + si * tg;
            const float tc = 1.f - 2.f / (__expf(2.f * cn) + 1.f);
            const float hn = so * tc;

            const int nxt = cur ^ 1;
            if (t < P_my) { c = cn; zbuf[nxt][(4*lq)*ZP + 64 + unit] = f2bf(hn); }
            cur = nxt;
        }

        // epilogue: pred_{maxP-1} from h_{maxP}
        bar_lds();
        if (predw) {
            const unsigned short* zc = zbuf[cur];
            bf16x8 h0f = *(const bf16x8*)(zc + abase + 64 +  0);
            bf16x8 h1f = *(const bf16x8*)(zc + abase + 64 + 32);
            bf16x8 h2f = *(const bf16x8*)(zc + abase + 64 + 64);
            bf16x8 h3f = *(const bf16x8*)(zc + abase + 64 + 96);
            f32x4 pa = {0.f,0.f,0.f,0.f}, pb = {0.f,0.f,0.f,0.f};
            pa = __builtin_amdgcn_mfma_f32_16x16x32_bf16(h0f, wd0, pa, 0,0,0);
            pb = __builtin_amdgcn_mfma_f32_16x16x32_bf16(h2f, wd2, pb, 0,0,0);
            pa = __builtin_amdgcn_mfma_f32_16x16x32_bf16(h1f, wd1, pa, 0,0,0);
            pb = __builtin_amdgcn_mfma_f32_16x16x32_bf16(h3f, wd3, pb, 0,0,0);
            if ((maxP - 1) < P_my)
                outb[(size_t)(maxP-1) * OUTS] = pa[0] + pb[0] + bden;
        }
    }

    // ============ MERGED TAIL: out[t][r][f] = x[r][f][t] for t >= P_r =======
    #pragma unroll 1
    for (int q = 0; q < 4; ++q) {
        const int r = perm[b0 + q];
        const int P = predict_len[r];
        if (P >= SS) continue;
        const float* xr = x + (size_t)r * FF * SS;
        for (int t0 = (P >> 6) << 6; t0 < SS; t0 += 64) {
            bar_lds();                                 // tile reusable
            {
                const int tt = tid & 63;
                const int fb = tid >> 6;               // 0..7
                #pragma unroll
                for (int i = 0; i < 8; ++i) {
                    const int f = fb * 8 + i;
                    tile[f][tt] = xr[(size_t)f * SS + t0 + tt];
                }
            }
            bar_lds();                                 // tile filled
            {
                const int f2 = tid & 63;
                const int tb = tid >> 6;               // 0..7
                #pragma unroll
                for (int i = 0; i < 8; ++i) {
                    const int tloc = tb * 8 + i;
                    const int t = t0 + tloc;
                    if (t >= P)
                        out[(size_t)t * OUTS + (size_t)r * FF + f2] = tile[f2][tloc];
                }
            }
        }
    }
}

extern "C" void kernel_launch(void* const* d_in, const int* in_sizes, int n_in,
                              void* d_out, int out_size, void* d_ws, size_t ws_size,
                              hipStream_t stream) {
    const float* x       = (const float*)d_in[0];
    const int*   avail   = (const int*)  d_in[1];
    const int*   plen    = (const int*)  d_in[2];
    const float* W_ih    = (const float*)d_in[3];
    const float* W_hh    = (const float*)d_in[4];
    const float* b_ih    = (const float*)d_in[5];
    const float* b_hh    = (const float*)d_in[6];
    const float* W_den   = (const float*)d_in[7];
    const float* b_den   = (const float*)d_in[8];
    const float* init_ch = (const float*)d_in[9];
    float*       out     = (float*)d_out;
    float*       ws      = (float*)d_ws;       // 264KB fold + 4KB perm
    int*         perm    = (int*)(ws + 4*HH*HH + 4*HH);

    fold_kernel<<<dim3(4*HH), dim3(HH), 0, stream>>>(W_ih, W_den, b_den, ws);
    sort_kernel<<<dim3(4), dim3(256), 0, stream>>>(avail, perm);
    lstm_mfma_kernel<<<dim3(BB/4), dim3(512), 0, stream>>>(
        x, avail, plen, W_ih, W_hh, b_ih, b_hh, W_den, b_den, init_ch, ws, perm, out);
}